// Round 2
// baseline (823.122 us; speedup 1.0000x reference)
//
#include <hip/hip_runtime.h>

typedef __attribute__((ext_vector_type(8))) short short8;
typedef __attribute__((ext_vector_type(4))) float floatx4;

// Problem dims (fixed): B=32, S=2048, E=1024, H=1024. M = B*S = 65536.

__device__ __forceinline__ unsigned short f2bf(float f) {
    unsigned u = __float_as_uint(f);
    return (unsigned short)((u + 0x7FFFu + ((u >> 16) & 1u)) >> 16);  // RTN-even
}
__device__ __forceinline__ unsigned pack2(float a, float b) {
    return (unsigned)f2bf(a) | ((unsigned)f2bf(b) << 16);
}

// ---- K1a: csum[h] = sum_g M_w[g, 1024+h]  (column sums of right half) ----
__global__ __launch_bounds__(256) void csum_kernel(const float* __restrict__ Mw,
                                                   float* __restrict__ csum) {
    int j = blockIdx.x;                  // 32 blocks: 4 h-chunks x 8 g-splits
    int h = (j & 3) * 256 + threadIdx.x;
    int g0 = (j >> 2) * 128;
    float p = 0.f;
    #pragma unroll 8
    for (int g = g0; g < g0 + 128; ++g) p += Mw[(size_t)g * 2048 + 1024 + h];
    atomicAdd(&csum[h], p);
}

// ---- K1b: hbias[b,h] = hidden[b,h]*csum[h] + Mb[h] ----
__global__ __launch_bounds__(256) void hbias_kernel(const float* __restrict__ hidden,
                                                    const float* __restrict__ csum,
                                                    const float* __restrict__ Mb,
                                                    float* __restrict__ hbias) {
    int b = blockIdx.x;  // 32
    #pragma unroll
    for (int i = 0; i < 4; ++i) {
        int h = i * 256 + threadIdx.x;
        hbias[b * 1024 + h] = hidden[b * 1024 + h] * csum[h] + Mb[h];
    }
}

// ---- K2: fused GEMM (enc @ MwE^T) + hbias + tanh + dot(V_w) -> partial scores ----
// 128x128 tile, BK=32, 4 waves (2x2), 16x16x32 bf16 MFMA, dbuf LDS, reg-staged f32->bf16.
__global__ __launch_bounds__(256) void gemm_scores(const float* __restrict__ A,   // enc 65536 x 1024
                                                   const float* __restrict__ Mw,  // 1024 x 2048 (use cols 0..1023)
                                                   const float* __restrict__ hbias,
                                                   const float* __restrict__ Vw,
                                                   float* __restrict__ scores) {
    __shared__ unsigned short As[2][128][32];
    __shared__ unsigned short Bs[2][128][32];

    // XCD-aware swizzle: 4096 blocks, 8 XCDs, ntile-fast so the 8 siblings of an
    // A-panel are contiguous within one XCD chunk (L2 reuse of the A panel).
    int bid = blockIdx.x;
    int wg = (bid & 7) * (gridDim.x >> 3) + (bid >> 3);
    int mtile = wg >> 3;   // 512 M-tiles
    int ntile = wg & 7;    // 8 N-tiles

    int t = threadIdx.x;
    int r = t >> 1, cg = (t & 1) * 16;   // each thread: 1 row, 16 of 32 k-cols
    const float* Ap = A  + (size_t)(mtile * 128 + r) * 1024 + cg;
    const float* Bp = Mw + (size_t)(ntile * 128 + r) * 2048 + cg;

    float4 a0, a1, a2, a3, b0, b1, b2, b3;
#define LOADT(KT) { const float* ap = Ap + (KT) * 32;                              \
        a0 = *(const float4*)ap;        a1 = *(const float4*)(ap + 4);             \
        a2 = *(const float4*)(ap + 8);  a3 = *(const float4*)(ap + 12);            \
        const float* bp = Bp + (KT) * 32;                                          \
        b0 = *(const float4*)bp;        b1 = *(const float4*)(bp + 4);             \
        b2 = *(const float4*)(bp + 8);  b3 = *(const float4*)(bp + 12); }
#define WRITET(BUF) { uint4 w;                                                     \
        w.x = pack2(a0.x,a0.y); w.y = pack2(a0.z,a0.w);                            \
        w.z = pack2(a1.x,a1.y); w.w = pack2(a1.z,a1.w);                            \
        *(uint4*)&As[BUF][r][cg] = w;                                              \
        w.x = pack2(a2.x,a2.y); w.y = pack2(a2.z,a2.w);                            \
        w.z = pack2(a3.x,a3.y); w.w = pack2(a3.z,a3.w);                            \
        *(uint4*)&As[BUF][r][cg + 8] = w;                                          \
        w.x = pack2(b0.x,b0.y); w.y = pack2(b0.z,b0.w);                            \
        w.z = pack2(b1.x,b1.y); w.w = pack2(b1.z,b1.w);                            \
        *(uint4*)&Bs[BUF][r][cg] = w;                                              \
        w.x = pack2(b2.x,b2.y); w.y = pack2(b2.z,b2.w);                            \
        w.z = pack2(b3.x,b3.y); w.w = pack2(b3.z,b3.w);                            \
        *(uint4*)&Bs[BUF][r][cg + 8] = w; }

    int lane = t & 63, wave = t >> 6;
    int wr = wave >> 1, wc = wave & 1;      // 2x2 wave grid, 64x64 per wave
    int l15 = lane & 15, l4 = lane >> 4;

    floatx4 zero = {0.f, 0.f, 0.f, 0.f};
    floatx4 acc[4][4];
    #pragma unroll
    for (int m = 0; m < 4; ++m)
        #pragma unroll
        for (int n = 0; n < 4; ++n) acc[m][n] = zero;

    LOADT(0);
    WRITET(0);

    #pragma unroll 2
    for (int kt = 0; kt < 32; ++kt) {
        int cur = kt & 1;
        __syncthreads();                  // stage(cur) visible; prev reads of cur^1 done
        if (kt < 31) LOADT(kt + 1);       // issue next-tile global loads (in flight over MFMA)
        short8 af[4], bf[4];
        #pragma unroll
        for (int m = 0; m < 4; ++m)
            af[m] = *(const short8*)&As[cur][wr * 64 + m * 16 + l15][l4 * 8];
        #pragma unroll
        for (int n = 0; n < 4; ++n)
            bf[n] = *(const short8*)&Bs[cur][wc * 64 + n * 16 + l15][l4 * 8];
        #pragma unroll
        for (int m = 0; m < 4; ++m)
            #pragma unroll
            for (int n = 0; n < 4; ++n)
                acc[m][n] = __builtin_amdgcn_mfma_f32_16x16x32_bf16(af[m], bf[n], acc[m][n], 0, 0, 0);
        if (kt < 31) WRITET(cur ^ 1);     // convert + write into other buffer
    }

    // Epilogue: val = tanh(acc + hbias[b,h]) * Vw[h]; reduce over this block's 128 cols.
    int b = mtile >> 4;                        // 2048/128 = 16 M-tiles per batch row
    int rowbase = mtile * 128 + wr * 64;
    int colbase = ntile * 128 + wc * 64;
    float vw[4], hb[4];
    #pragma unroll
    for (int n = 0; n < 4; ++n) {
        int h = colbase + n * 16 + l15;
        vw[n] = Vw[h];
        hb[n] = hbias[b * 1024 + h];
    }
    #pragma unroll
    for (int m = 0; m < 4; ++m) {
        #pragma unroll
        for (int j = 0; j < 4; ++j) {
            float s = 0.f;
            #pragma unroll
            for (int n = 0; n < 4; ++n)
                s += tanhf(acc[m][n][j] + hb[n]) * vw[n];
            s += __shfl_xor(s, 1); s += __shfl_xor(s, 2);
            s += __shfl_xor(s, 4); s += __shfl_xor(s, 8);   // sum over 16 cols (l15)
            if (l15 == 0)
                atomicAdd(&scores[rowbase + m * 16 + l4 * 4 + j], s);
        }
    }
#undef LOADT
#undef WRITET
}

// ---- K3: masked softmax per batch row; writes weights (f32) ----
__global__ __launch_bounds__(256) void softmax_kernel(const float* __restrict__ scores,
                                                      const int* __restrict__ mask,
                                                      const float* __restrict__ Vb,
                                                      float* __restrict__ wout) {
    int b = blockIdx.x, t = threadIdx.x;
    float vb = Vb[0];
    float v[8];
    float mx = -3.4e38f;
    #pragma unroll
    for (int i = 0; i < 8; ++i) {
        int s = i * 256 + t;
        float sc = scores[b * 2048 + s] + vb;
        sc = mask[b * 2048 + s] ? -1e30f : sc;   // mask==True -> excluded
        v[i] = sc;
        mx = fmaxf(mx, sc);
    }
    #pragma unroll
    for (int off = 32; off; off >>= 1) mx = fmaxf(mx, __shfl_xor(mx, off));
    __shared__ float sm[4], ss[4];
    int wv = t >> 6, ln = t & 63;
    if (!ln) sm[wv] = mx;
    __syncthreads();
    mx = fmaxf(fmaxf(sm[0], sm[1]), fmaxf(sm[2], sm[3]));
    float sum = 0.f;
    #pragma unroll
    for (int i = 0; i < 8; ++i) { v[i] = __expf(v[i] - mx); sum += v[i]; }
    #pragma unroll
    for (int off = 32; off; off >>= 1) sum += __shfl_xor(sum, off);
    if (!ln) ss[wv] = sum;
    __syncthreads();
    sum = ss[0] + ss[1] + ss[2] + ss[3];
    float inv = 1.0f / sum;
    #pragma unroll
    for (int i = 0; i < 8; ++i) wout[b * 2048 + i * 256 + t] = v[i] * inv;
}

// ---- K4: weighted[b,e] = sum_s w[b,s] * enc[b,s,e] ----
__global__ __launch_bounds__(256) void weighted_kernel(const float* __restrict__ enc,
                                                       const float* __restrict__ w,
                                                       float* __restrict__ out) {
    int blk = blockIdx.x;            // 32 b x 4 e-chunks x 8 s-segments = 1024
    int b = blk >> 5;
    int ec = (blk >> 3) & 3;
    int ssg = blk & 7;
    int e = ec * 256 + threadIdx.x;
    const float* encb = enc + ((size_t)b * 2048 + ssg * 256) * 1024 + e;
    const float* wb = w + b * 2048 + ssg * 256;
    float acc = 0.f;
    #pragma unroll 8
    for (int s = 0; s < 256; ++s) acc += wb[s] * encb[(size_t)s * 1024];
    atomicAdd(&out[b * 1024 + e], acc);
}

extern "C" void kernel_launch(void* const* d_in, const int* in_sizes, int n_in,
                              void* d_out, int out_size, void* d_ws, size_t ws_size,
                              hipStream_t stream) {
    (void)in_sizes; (void)n_in; (void)ws_size;
    const float* hidden = (const float*)d_in[0];   // 32 x 1 x 1024
    const float* enc    = (const float*)d_in[1];   // 32 x 2048 x 1024
    const int*   mask   = (const int*)d_in[2];     // 32 x 2048 (0/1)
    const float* Mw     = (const float*)d_in[3];   // 1024 x 2048
    const float* Mb     = (const float*)d_in[4];   // 1024
    const float* Vw     = (const float*)d_in[5];   // 1024
    const float* Vb     = (const float*)d_in[6];   // 1

    float* out    = (float*)d_out;                 // [0,32768) weighted | [32768,98304) weights
    float* scores = (float*)d_ws;                  // 65536 f32
    float* csum   = scores + 65536;                // 1024 f32
    float* hbias  = csum + 1024;                   // 32768 f32

    hipMemsetAsync(d_out, 0, (size_t)out_size * sizeof(float), stream);
    hipMemsetAsync(d_ws, 0, (65536 + 1024) * sizeof(float), stream);  // scores + csum

    hipLaunchKernelGGL(csum_kernel,    dim3(32),   dim3(256), 0, stream, Mw, csum);
    hipLaunchKernelGGL(hbias_kernel,   dim3(32),   dim3(256), 0, stream, hidden, csum, Mb, hbias);
    hipLaunchKernelGGL(gemm_scores,    dim3(4096), dim3(256), 0, stream, enc, Mw, hbias, Vw, scores);
    hipLaunchKernelGGL(softmax_kernel, dim3(32),   dim3(256), 0, stream, scores, mask, Vb, out + 32768);
    hipLaunchKernelGGL(weighted_kernel,dim3(1024), dim3(256), 0, stream, enc, out + 32768, out);
}

// Round 3
// 688.887 us; speedup vs baseline: 1.1949x; 1.1949x over previous
//
#include <hip/hip_runtime.h>

typedef __attribute__((ext_vector_type(8))) short short8;
typedef __attribute__((ext_vector_type(4))) float floatx4;

// Problem dims (fixed): B=32, S=2048, E=1024, H=1024. M = B*S = 65536.

__device__ __forceinline__ unsigned short f2bf(float f) {
    unsigned u = __float_as_uint(f);
    return (unsigned short)((u + 0x7FFFu + ((u >> 16) & 1u)) >> 16);  // RTN-even
}
__device__ __forceinline__ unsigned pack2(float a, float b) {
    return (unsigned)f2bf(a) | ((unsigned)f2bf(b) << 16);
}
__device__ __forceinline__ float bf2f(unsigned short v) {
    return __uint_as_float(((unsigned)v) << 16);
}
__device__ __forceinline__ float fast_tanh(float x) {
    float e = __expf(2.f * x);              // inf-safe: x>>0 -> 1, x<<0 -> -1
    return 1.f - 2.f / (e + 1.f);
}
__device__ __forceinline__ void gll16(const void* g, void* l) {
    __builtin_amdgcn_global_load_lds(
        (const __attribute__((address_space(1))) unsigned int*)g,
        (__attribute__((address_space(3))) unsigned int*)l, 16, 0, 0);
}

// ---- K0a: enc f32 -> bf16 (64M elems) ----
__global__ __launch_bounds__(256) void conv_enc(const float* __restrict__ in,
                                                unsigned short* __restrict__ ob) {
    size_t idx = (size_t)blockIdx.x * 256 + threadIdx.x;
    const size_t stride = (size_t)gridDim.x * 256;
    const size_t n8 = 67108864 / 8;
    for (size_t i = idx; i < n8; i += stride) {
        float4 f0 = ((const float4*)in)[2 * i];
        float4 f1 = ((const float4*)in)[2 * i + 1];
        uint4 w;
        w.x = pack2(f0.x, f0.y); w.y = pack2(f0.z, f0.w);
        w.z = pack2(f1.x, f1.y); w.w = pack2(f1.z, f1.w);
        ((uint4*)ob)[i] = w;
    }
}

// ---- K0b: Mw[:, 0:1024] f32 (stride 2048) -> bf16 1024x1024 ----
__global__ __launch_bounds__(256) void conv_mw(const float* __restrict__ Mw,
                                               unsigned short* __restrict__ ob) {
    int r = blockIdx.x;           // 1024
    int c = threadIdx.x * 4;
    float4 f = *(const float4*)&Mw[(size_t)r * 2048 + c];
    uint2 w; w.x = pack2(f.x, f.y); w.y = pack2(f.z, f.w);
    *(uint2*)&ob[r * 1024 + c] = w;
}

// ---- K1a: csum[h] = sum_g M_w[g, 1024+h] ----
__global__ __launch_bounds__(256) void csum_kernel(const float* __restrict__ Mw,
                                                   float* __restrict__ csum) {
    int j = blockIdx.x;
    int h = (j & 3) * 256 + threadIdx.x;
    int g0 = (j >> 2) * 128;
    float p = 0.f;
    #pragma unroll 8
    for (int g = g0; g < g0 + 128; ++g) p += Mw[(size_t)g * 2048 + 1024 + h];
    atomicAdd(&csum[h], p);
}

// ---- K1b: hbias[b,h] = hidden[b,h]*csum[h] + Mb[h] ----
__global__ __launch_bounds__(256) void hbias_kernel(const float* __restrict__ hidden,
                                                    const float* __restrict__ csum,
                                                    const float* __restrict__ Mb,
                                                    float* __restrict__ hbias) {
    int b = blockIdx.x;
    #pragma unroll
    for (int i = 0; i < 4; ++i) {
        int h = i * 256 + threadIdx.x;
        hbias[b * 1024 + h] = hidden[b * 1024 + h] * csum[h] + Mb[h];
    }
}

// ---- K2 (fast): m97-structure GEMM on bf16 inputs + fused tanh/dot epilogue ----
// 128x128 tile, BK=64, global_load_lds x16, linear LDS, 2-barrier loop, 3 blk/CU.
__global__ __launch_bounds__(256, 3) void gemm_scores2(const unsigned short* __restrict__ Ab,  // 65536x1024 bf16
                                                       const unsigned short* __restrict__ Bb,  // 1024x1024 bf16
                                                       const float* __restrict__ hbias,
                                                       const float* __restrict__ Vw,
                                                       float* __restrict__ scores) {
    __shared__ unsigned short As[128][64];
    __shared__ unsigned short Bs[128][64];

    int bid = blockIdx.x;
    int wg = (bid & 7) * (gridDim.x >> 3) + (bid >> 3);   // XCD swizzle, ntile-fast
    int mtile = wg >> 3;   // 512
    int ntile = wg & 7;    // 8

    int t = threadIdx.x, lane = t & 63, wave = t >> 6;
    int wr = wave >> 1, wc = wave & 1;
    int l15 = lane & 15, l4 = lane >> 4;

    const unsigned short* Abase = Ab + (size_t)(mtile * 128) * 1024;
    const unsigned short* Bbase = Bb + (size_t)(ntile * 128) * 1024;

    // staging geometry: elem = i*2048 + wave*512 + lane*8 ; row=elem>>6 ; k=elem&63
    int e0 = wave * 512 + lane * 8;

    floatx4 zero = {0.f, 0.f, 0.f, 0.f};
    floatx4 acc[4][4];
    #pragma unroll
    for (int m = 0; m < 4; ++m)
        #pragma unroll
        for (int n = 0; n < 4; ++n) acc[m][n] = zero;

    for (int kt = 0; kt < 16; ++kt) {
        int k0 = kt * 64;
        #pragma unroll
        for (int i = 0; i < 4; ++i) {
            int elem = i * 2048 + e0;
            int row = elem >> 6, kk = elem & 63;
            gll16(Abase + (size_t)row * 1024 + k0 + kk, &As[row][kk]);
            gll16(Bbase + (size_t)row * 1024 + k0 + kk, &Bs[row][kk]);
        }
        __syncthreads();                       // drains vmcnt(0) + barrier
        short8 af[2][4], bf[2][4];
        #pragma unroll
        for (int ks = 0; ks < 2; ++ks) {
            #pragma unroll
            for (int m = 0; m < 4; ++m)
                af[ks][m] = *(const short8*)&As[wr * 64 + m * 16 + l15][ks * 32 + l4 * 8];
            #pragma unroll
            for (int n = 0; n < 4; ++n)
                bf[ks][n] = *(const short8*)&Bs[wc * 64 + n * 16 + l15][ks * 32 + l4 * 8];
        }
        #pragma unroll
        for (int ks = 0; ks < 2; ++ks)
            #pragma unroll
            for (int m = 0; m < 4; ++m)
                #pragma unroll
                for (int n = 0; n < 4; ++n)
                    acc[m][n] = __builtin_amdgcn_mfma_f32_16x16x32_bf16(af[ks][m], bf[ks][n], acc[m][n], 0, 0, 0);
        __syncthreads();                       // LDS reads done before next stage
    }

    // Epilogue: s = sum_h tanh(acc + hbias[b,h]) * Vw[h], reduced over 128 cols.
    int b = mtile >> 4;
    int rowbase = mtile * 128 + wr * 64;
    int colbase = ntile * 128 + wc * 64;
    float vw[4], hb[4];
    #pragma unroll
    for (int n = 0; n < 4; ++n) {
        int h = colbase + n * 16 + l15;
        vw[n] = Vw[h];
        hb[n] = hbias[b * 1024 + h];
    }
    #pragma unroll
    for (int m = 0; m < 4; ++m) {
        #pragma unroll
        for (int j = 0; j < 4; ++j) {
            float s = 0.f;
            #pragma unroll
            for (int n = 0; n < 4; ++n)
                s += fast_tanh(acc[m][n][j] + hb[n]) * vw[n];
            s += __shfl_xor(s, 1); s += __shfl_xor(s, 2);
            s += __shfl_xor(s, 4); s += __shfl_xor(s, 8);
            if (l15 == 0)
                atomicAdd(&scores[rowbase + m * 16 + l4 * 4 + j], s);
        }
    }
}

// ---- K2 (fallback, round-2 reg-staged version) ----
__global__ __launch_bounds__(256) void gemm_scores(const float* __restrict__ A,
                                                   const float* __restrict__ Mw,
                                                   const float* __restrict__ hbias,
                                                   const float* __restrict__ Vw,
                                                   float* __restrict__ scores) {
    __shared__ unsigned short As[2][128][32];
    __shared__ unsigned short Bs[2][128][32];
    int bid = blockIdx.x;
    int wg = (bid & 7) * (gridDim.x >> 3) + (bid >> 3);
    int mtile = wg >> 3, ntile = wg & 7;
    int t = threadIdx.x;
    int r = t >> 1, cg = (t & 1) * 16;
    const float* Ap = A  + (size_t)(mtile * 128 + r) * 1024 + cg;
    const float* Bp = Mw + (size_t)(ntile * 128 + r) * 2048 + cg;
    float4 a0, a1, a2, a3, b0, b1, b2, b3;
#define LOADT(KT) { const float* ap = Ap + (KT) * 32;                              \
        a0 = *(const float4*)ap;        a1 = *(const float4*)(ap + 4);             \
        a2 = *(const float4*)(ap + 8);  a3 = *(const float4*)(ap + 12);            \
        const float* bp = Bp + (KT) * 32;                                          \
        b0 = *(const float4*)bp;        b1 = *(const float4*)(bp + 4);             \
        b2 = *(const float4*)(bp + 8);  b3 = *(const float4*)(bp + 12); }
#define WRITET(BUF) { uint4 w;                                                     \
        w.x = pack2(a0.x,a0.y); w.y = pack2(a0.z,a0.w);                            \
        w.z = pack2(a1.x,a1.y); w.w = pack2(a1.z,a1.w);                            \
        *(uint4*)&As[BUF][r][cg] = w;                                              \
        w.x = pack2(a2.x,a2.y); w.y = pack2(a2.z,a2.w);                            \
        w.z = pack2(a3.x,a3.y); w.w = pack2(a3.z,a3.w);                            \
        *(uint4*)&As[BUF][r][cg + 8] = w;                                          \
        w.x = pack2(b0.x,b0.y); w.y = pack2(b0.z,b0.w);                            \
        w.z = pack2(b1.x,b1.y); w.w = pack2(b1.z,b1.w);                            \
        *(uint4*)&Bs[BUF][r][cg] = w;                                              \
        w.x = pack2(b2.x,b2.y); w.y = pack2(b2.z,b2.w);                            \
        w.z = pack2(b3.x,b3.y); w.w = pack2(b3.z,b3.w);                            \
        *(uint4*)&Bs[BUF][r][cg + 8] = w; }
    int lane = t & 63, wave = t >> 6;
    int wr = wave >> 1, wc = wave & 1;
    int l15 = lane & 15, l4 = lane >> 4;
    floatx4 zero = {0.f, 0.f, 0.f, 0.f};
    floatx4 acc[4][4];
    #pragma unroll
    for (int m = 0; m < 4; ++m)
        #pragma unroll
        for (int n = 0; n < 4; ++n) acc[m][n] = zero;
    LOADT(0); WRITET(0);
    #pragma unroll 2
    for (int kt = 0; kt < 32; ++kt) {
        int cur = kt & 1;
        __syncthreads();
        if (kt < 31) LOADT(kt + 1);
        short8 af[4], bf[4];
        #pragma unroll
        for (int m = 0; m < 4; ++m)
            af[m] = *(const short8*)&As[cur][wr * 64 + m * 16 + l15][l4 * 8];
        #pragma unroll
        for (int n = 0; n < 4; ++n)
            bf[n] = *(const short8*)&Bs[cur][wc * 64 + n * 16 + l15][l4 * 8];
        #pragma unroll
        for (int m = 0; m < 4; ++m)
            #pragma unroll
            for (int n = 0; n < 4; ++n)
                acc[m][n] = __builtin_amdgcn_mfma_f32_16x16x32_bf16(af[m], bf[n], acc[m][n], 0, 0, 0);
        if (kt < 31) WRITET(cur ^ 1);
    }
    int b = mtile >> 4;
    int rowbase = mtile * 128 + wr * 64;
    int colbase = ntile * 128 + wc * 64;
    float vw[4], hb[4];
    #pragma unroll
    for (int n = 0; n < 4; ++n) {
        int h = colbase + n * 16 + l15;
        vw[n] = Vw[h];
        hb[n] = hbias[b * 1024 + h];
    }
    #pragma unroll
    for (int m = 0; m < 4; ++m) {
        #pragma unroll
        for (int j = 0; j < 4; ++j) {
            float s = 0.f;
            #pragma unroll
            for (int n = 0; n < 4; ++n)
                s += fast_tanh(acc[m][n][j] + hb[n]) * vw[n];
            s += __shfl_xor(s, 1); s += __shfl_xor(s, 2);
            s += __shfl_xor(s, 4); s += __shfl_xor(s, 8);
            if (l15 == 0)
                atomicAdd(&scores[rowbase + m * 16 + l4 * 4 + j], s);
        }
    }
#undef LOADT
#undef WRITET
}

// ---- K3: masked softmax per batch row ----
__global__ __launch_bounds__(256) void softmax_kernel(const float* __restrict__ scores,
                                                      const int* __restrict__ mask,
                                                      const float* __restrict__ Vb,
                                                      float* __restrict__ wout) {
    int b = blockIdx.x, t = threadIdx.x;
    float vb = Vb[0];
    float v[8];
    float mx = -3.4e38f;
    #pragma unroll
    for (int i = 0; i < 8; ++i) {
        int s = i * 256 + t;
        float sc = scores[b * 2048 + s] + vb;
        sc = mask[b * 2048 + s] ? -1e30f : sc;
        v[i] = sc;
        mx = fmaxf(mx, sc);
    }
    #pragma unroll
    for (int off = 32; off; off >>= 1) mx = fmaxf(mx, __shfl_xor(mx, off));
    __shared__ float sm[4], ss[4];
    int wv = t >> 6, ln = t & 63;
    if (!ln) sm[wv] = mx;
    __syncthreads();
    mx = fmaxf(fmaxf(sm[0], sm[1]), fmaxf(sm[2], sm[3]));
    float sum = 0.f;
    #pragma unroll
    for (int i = 0; i < 8; ++i) { v[i] = __expf(v[i] - mx); sum += v[i]; }
    #pragma unroll
    for (int off = 32; off; off >>= 1) sum += __shfl_xor(sum, off);
    if (!ln) ss[wv] = sum;
    __syncthreads();
    sum = ss[0] + ss[1] + ss[2] + ss[3];
    float inv = 1.0f / sum;
    #pragma unroll
    for (int i = 0; i < 8; ++i) wout[b * 2048 + i * 256 + t] = v[i] * inv;
}

// ---- K4 (fast): weighted[b,e] = sum_s w[b,s]*enc_bf16[b,s,e], short8 loads ----
__global__ __launch_bounds__(256) void weighted2(const unsigned short* __restrict__ encb,
                                                 const float* __restrict__ w,
                                                 float* __restrict__ out) {
    int blk = blockIdx.x;                 // 32 b x 16 ssegs = 512
    int b = blk >> 4, sseg = blk & 15;    // 128 rows per sseg
    int t = threadIdx.x;
    int e0 = (t & 127) * 8;
    int sr = t >> 7;                      // row parity
    const unsigned short* base = encb + ((size_t)b * 2048 + sseg * 128 + sr) * 1024 + e0;
    const float* wb = w + b * 2048 + sseg * 128 + sr;
    float acc[8] = {0, 0, 0, 0, 0, 0, 0, 0};
    #pragma unroll 4
    for (int s = 0; s < 128; s += 2) {
        float ws = wb[s];
        short8 v = *(const short8*)(base + (size_t)s * 1024);
        #pragma unroll
        for (int j = 0; j < 8; ++j)
            acc[j] += ws * bf2f((unsigned short)v[j]);
    }
    #pragma unroll
    for (int j = 0; j < 8; ++j)
        atomicAdd(&out[b * 1024 + e0 + j], acc[j]);
}

// ---- K4 (fallback, f32) ----
__global__ __launch_bounds__(256) void weighted_kernel(const float* __restrict__ enc,
                                                       const float* __restrict__ w,
                                                       float* __restrict__ out) {
    int blk = blockIdx.x;
    int b = blk >> 5;
    int ec = (blk >> 3) & 3;
    int ssg = blk & 7;
    int e = ec * 256 + threadIdx.x;
    const float* encb = enc + ((size_t)b * 2048 + ssg * 256) * 1024 + e;
    const float* wb = w + b * 2048 + ssg * 256;
    float acc = 0.f;
    #pragma unroll 8
    for (int s = 0; s < 256; ++s) acc += wb[s] * encb[(size_t)s * 1024];
    atomicAdd(&out[b * 1024 + e], acc);
}

extern "C" void kernel_launch(void* const* d_in, const int* in_sizes, int n_in,
                              void* d_out, int out_size, void* d_ws, size_t ws_size,
                              hipStream_t stream) {
    (void)in_sizes; (void)n_in; (void)out_size;
    const float* hidden = (const float*)d_in[0];
    const float* enc    = (const float*)d_in[1];
    const int*   mask   = (const int*)d_in[2];
    const float* Mw     = (const float*)d_in[3];
    const float* Mb     = (const float*)d_in[4];
    const float* Vw     = (const float*)d_in[5];
    const float* Vb     = (const float*)d_in[6];
    float* out = (float*)d_out;   // [0,32768) weighted | [32768,98304) weights

    const size_t ENC_N = 67108864;           // 64M bf16
    const size_t MW_N  = 1048576;            // 1M bf16
    const size_t need  = ENC_N * 2 + MW_N * 2 + (65536 + 1024 + 32768) * 4;

    if (ws_size >= need) {
        unsigned short* encb = (unsigned short*)d_ws;
        unsigned short* Mwb  = encb + ENC_N;
        float* scores = (float*)(Mwb + MW_N);
        float* csum   = scores + 65536;
        float* hbias  = csum + 1024;

        hipMemsetAsync(out, 0, 32768 * sizeof(float), stream);
        hipMemsetAsync(scores, 0, (65536 + 1024) * sizeof(float), stream);

        hipLaunchKernelGGL(conv_enc,       dim3(2048), dim3(256), 0, stream, enc, encb);
        hipLaunchKernelGGL(conv_mw,        dim3(1024), dim3(256), 0, stream, Mw, Mwb);
        hipLaunchKernelGGL(csum_kernel,    dim3(32),   dim3(256), 0, stream, Mw, csum);
        hipLaunchKernelGGL(hbias_kernel,   dim3(32),   dim3(256), 0, stream, hidden, csum, Mb, hbias);
        hipLaunchKernelGGL(gemm_scores2,   dim3(4096), dim3(256), 0, stream, encb, Mwb, hbias, Vw, scores);
        hipLaunchKernelGGL(softmax_kernel, dim3(32),   dim3(256), 0, stream, scores, mask, Vb, out + 32768);
        hipLaunchKernelGGL(weighted2,      dim3(512),  dim3(256), 0, stream, encb, out + 32768, out);
    } else {
        float* scores = (float*)d_ws;
        float* csum   = scores + 65536;
        float* hbias  = csum + 1024;
        hipMemsetAsync(out, 0, 32768 * sizeof(float), stream);
        hipMemsetAsync(scores, 0, (65536 + 1024) * sizeof(float), stream);
        hipLaunchKernelGGL(csum_kernel,    dim3(32),   dim3(256), 0, stream, Mw, csum);
        hipLaunchKernelGGL(hbias_kernel,   dim3(32),   dim3(256), 0, stream, hidden, csum, Mb, hbias);
        hipLaunchKernelGGL(gemm_scores,    dim3(4096), dim3(256), 0, stream, enc, Mw, hbias, Vw, scores);
        hipLaunchKernelGGL(softmax_kernel, dim3(32),   dim3(256), 0, stream, scores, mask, Vb, out + 32768);
        hipLaunchKernelGGL(weighted_kernel,dim3(1024), dim3(256), 0, stream, enc, out + 32768, out);
    }
}